// Round 7
// baseline (169.564 us; speedup 1.0000x reference)
//
#include <hip/hip_runtime.h>

// PointnetFPModule: three_nn (brute force, top-3 smallest d2) + three_interpolate.
// Shapes: B=8, N=8192, M=2048, C=256.  All fp32.
// unknown (B,N,3), known (B,M,3), known_feats (B,C,M) -> out (B,C,N)
//
// R7: scan was VALU-issue-bound (~29 eff ops/pair). Two-pass threshold scan:
//  stage1: r = |k|^2 - 2u.k via 3 FMA + 3-op branchless top-3 (no indices)
//  merge -> per-point threshold T = 3rd-smallest r + 1e-4 margin
//  stage2: recompute r bit-identically; rare wave-branch (~33% of cand steps)
//          computes canonical bit-exact d2 + stable indexed insert.
// Margin proof: top-3-by-d2 candidates have r <= T + margin for margin >>
// 2*eps_r + 2*eps_d (~6e-6); 1e-4 gives 15x headroom; over-capture is safe
// (stage2 ranks exactly, ascending (chunk, m) order preserves top_k ties).
// Retile PPT=4 (8 waves, 256 pts/block, grid 256) to amortize LDS broadcasts.

#define BB 8
#define NN 8192
#define MM 2048
#define CC 256
#define EPSV 1e-8f
#define NTH 512          // 8 waves
#define NCH 8            // chunks = waves
#define CHUNK (MM/NCH)   // 256
#define PPT 4            // points per thread
#define PTS 256          // points per block = 64 lanes * PPT
#define MARGIN 1e-4f
#define TC 4             // channels per interp block

// Branchy stable insert: strict < keeps lowest index on ties; candidates
// arrive in ascending-index order => matches jax.lax.top_k.
#define INS(dd, mi, D0,I0,D1,I1,D2,I2) \
    if ((dd) < D2) { \
        if ((dd) < D1) { D2 = D1; I2 = I1; \
            if ((dd) < D0) { D1 = D0; I1 = I0; D0 = (dd); I0 = (mi); } \
            else           { D1 = (dd); I1 = (mi); } \
        } else { D2 = (dd); I2 = (mi); } }

// Proxy rank value: MUST be bit-identical in stage1 and stage2 (same macro,
// same LDS inputs -> same bits).
#define RF(KX,KY,KZ,KQ,J) \
    __fmaf_rn((KZ), az[J], __fmaf_rn((KY), ay[J], __fmaf_rn((KX), ax[J], (KQ))))

// Stage-1: branchless 3-smallest update (values only). Invariant R0<=R1<=R2.
#define S1(KX,KY,KZ,KQ,J) { \
    const float rr = RF(KX,KY,KZ,KQ,J); \
    R2[J] = __builtin_amdgcn_fmed3f(R1[J], R2[J], rr); \
    R1[J] = __builtin_amdgcn_fmed3f(R0[J], R1[J], rr); \
    R0[J] = fminf(R0[J], rr); }

// Stage-2 capture for one point: exact d2 matches numpy exactly (no FMA
// contraction, (x^2+y^2)+z^2 order).
#define CAP(RR,J,KX,KY,KZ,MI) \
    if ((RR) <= Tm[J]) { \
        const float dx = ux[J]-(KX), dy = uy[J]-(KY), dz = uz[J]-(KZ); \
        const float d = __fadd_rn(__fadd_rn(__fmul_rn(dx,dx),__fmul_rn(dy,dy)),__fmul_rn(dz,dz)); \
        INS(d, MI, D0[J],J0[J],D1[J],J1[J],D2[J],J2[J]) }

#define S2(KX,KY,KZ,KQ,MI) { \
    const float rr0 = RF(KX,KY,KZ,KQ,0); \
    const float rr1 = RF(KX,KY,KZ,KQ,1); \
    const float rr2 = RF(KX,KY,KZ,KQ,2); \
    const float rr3 = RF(KX,KY,KZ,KQ,3); \
    if (fminf(fminf(rr0,rr1),fminf(rr2,rr3)) <= Tmax) { \
        CAP(rr0,0,KX,KY,KZ,MI) \
        CAP(rr1,1,KX,KY,KZ,MI) \
        CAP(rr2,2,KX,KY,KZ,MI) \
        CAP(rr3,3,KX,KY,KZ,MI) } }

typedef unsigned short u16;

__global__ __launch_bounds__(NTH) void nn_scan_kernel(
    const float* __restrict__ unknown,
    const float* __restrict__ known,
    float4* __restrict__ wgt4,
    int4*  __restrict__ idx4)
{
    __shared__ float kxs[MM], kys[MM], kzs[MM], kqs[MM];   // 32 KB
    __shared__ float pd[NCH][PTS][3];                      // 24 KB (stage1 r-lists; stage2 reuse)
    __shared__ float Tarr[PTS];                            // 1 KB

    const int tilesPerBatch = NN / PTS;   // 32
    const int b    = blockIdx.x / tilesPerBatch;
    const int tile = blockIdx.x % tilesPerBatch;
    const int t    = threadIdx.x;
    const int lane = t & 63;
    const int g    = t >> 6;              // wave id == chunk id (uniform/wave)

    // ---- stage known[b] coords (AoS -> SoA) + |k|^2 ----
    const float* kb = known + (size_t)b * MM * 3;
    for (int idx = t; idx < MM * 3; idx += NTH) {
        const float v  = kb[idx];
        const int   a  = idx % 3;
        const int   mi = idx / 3;
        float* dst = (a == 0) ? kxs : ((a == 1) ? kys : kzs);
        dst[mi] = v;
    }
    __syncthreads();
    for (int m = t; m < MM; m += NTH) {
        const float x = kxs[m], y = kys[m], z = kzs[m];
        kqs[m] = __fmaf_rn(z, z, __fmaf_rn(y, y, x * x));
    }

    // ---- load 4 points per thread ----
    const float* ub = unknown + ((size_t)b * NN + (size_t)tile * PTS) * 3;
    float ux[PPT], uy[PPT], uz[PPT], ax[PPT], ay[PPT], az[PPT];
    #pragma unroll
    for (int j = 0; j < PPT; ++j) {
        const float* u = ub + (size_t)(lane + 64 * j) * 3;
        ux[j] = u[0]; uy[j] = u[1]; uz[j] = u[2];
        ax[j] = -2.0f * ux[j]; ay[j] = -2.0f * uy[j]; az[j] = -2.0f * uz[j];
    }
    __syncthreads();   // kqs ready

    // ---- stage 1: top-3 proxy values (no indices) ----
    float R0[PPT], R1[PPT], R2[PPT];
    #pragma unroll
    for (int j = 0; j < PPT; ++j) { R0[j] = 1e30f; R1[j] = 1e30f; R2[j] = 1e30f; }

    const int mbeg = g * CHUNK;
    #pragma unroll 4
    for (int m = mbeg; m < mbeg + CHUNK; m += 4) {
        const float4 x4 = *reinterpret_cast<const float4*>(&kxs[m]);
        const float4 y4 = *reinterpret_cast<const float4*>(&kys[m]);
        const float4 z4 = *reinterpret_cast<const float4*>(&kzs[m]);
        const float4 q4 = *reinterpret_cast<const float4*>(&kqs[m]);
        #pragma unroll
        for (int j = 0; j < PPT; ++j) {
            S1(x4.x, y4.x, z4.x, q4.x, j)
            S1(x4.y, y4.y, z4.y, q4.y, j)
            S1(x4.z, y4.z, z4.z, q4.z, j)
            S1(x4.w, y4.w, z4.w, q4.w, j)
        }
    }
    #pragma unroll
    for (int j = 0; j < PPT; ++j) {
        const int p = lane + 64 * j;
        pd[g][p][0] = R0[j]; pd[g][p][1] = R1[j]; pd[g][p][2] = R2[j];
    }
    __syncthreads();

    // ---- merge r-lists -> per-point threshold ----
    if (t < PTS) {
        float e0 = 1e30f, e1 = 1e30f, e2 = 1e30f;
        #pragma unroll
        for (int q = 0; q < NCH; ++q) {
            #pragma unroll
            for (int r = 0; r < 3; ++r) {
                const float d = pd[q][t][r];
                e2 = __builtin_amdgcn_fmed3f(e1, e2, d);
                e1 = __builtin_amdgcn_fmed3f(e0, e1, d);
                e0 = fminf(e0, d);
            }
        }
        Tarr[t] = e2 + MARGIN;
    }
    __syncthreads();

    // ---- stage 2: rescan, capture exact (d2, idx) for r <= T ----
    float D0[PPT], D1[PPT], D2[PPT];
    int   J0[PPT], J1[PPT], J2[PPT];
    float Tm[PPT];
    #pragma unroll
    for (int j = 0; j < PPT; ++j) {
        D0[j] = 1e30f; D1[j] = 1e30f; D2[j] = 1e30f;
        J0[j] = 0; J1[j] = 0; J2[j] = 0;
        Tm[j] = Tarr[lane + 64 * j];
    }
    const float Tmax = fmaxf(fmaxf(Tm[0], Tm[1]), fmaxf(Tm[2], Tm[3]));

    #pragma unroll 2
    for (int m = mbeg; m < mbeg + CHUNK; m += 4) {
        const float4 x4 = *reinterpret_cast<const float4*>(&kxs[m]);
        const float4 y4 = *reinterpret_cast<const float4*>(&kys[m]);
        const float4 z4 = *reinterpret_cast<const float4*>(&kzs[m]);
        const float4 q4 = *reinterpret_cast<const float4*>(&kqs[m]);
        S2(x4.x, y4.x, z4.x, q4.x, m)
        S2(x4.y, y4.y, z4.y, q4.y, m+1)
        S2(x4.z, y4.z, z4.z, q4.z, m+2)
        S2(x4.w, y4.w, z4.w, q4.w, m+3)
    }

    // ---- two-round writeback + stable merge (chunk asc, rank asc) ----
    float (*sd)[PTS][3] = pd;                                   // 12 KB: pd[0..3]
    u16 (*si)[PTS][3] = reinterpret_cast<u16 (*)[PTS][3]>(&pd[4][0][0]); // 6 KB: pd[4..5]

    if (g < 4) {
        #pragma unroll
        for (int j = 0; j < PPT; ++j) {
            const int p = lane + 64 * j;
            sd[g][p][0] = D0[j]; sd[g][p][1] = D1[j]; sd[g][p][2] = D2[j];
            si[g][p][0] = (u16)J0[j]; si[g][p][1] = (u16)J1[j]; si[g][p][2] = (u16)J2[j];
        }
    }
    __syncthreads();

    float e0 = 1e30f, e1 = 1e30f, e2 = 1e30f;
    int   j0 = 0,     j1 = 0,     j2 = 0;
    if (t < PTS) {
        #pragma unroll
        for (int q = 0; q < 4; ++q) {
            #pragma unroll
            for (int r = 0; r < 3; ++r) {
                const float d  = sd[q][t][r];
                const int   ii = (int)si[q][t][r];
                INS(d, ii, e0,j0,e1,j1,e2,j2)
            }
        }
    }
    __syncthreads();   // round-A reads done before overwrite

    if (g >= 4) {
        #pragma unroll
        for (int j = 0; j < PPT; ++j) {
            const int p = lane + 64 * j;
            sd[g-4][p][0] = D0[j]; sd[g-4][p][1] = D1[j]; sd[g-4][p][2] = D2[j];
            si[g-4][p][0] = (u16)J0[j]; si[g-4][p][1] = (u16)J1[j]; si[g-4][p][2] = (u16)J2[j];
        }
    }
    __syncthreads();

    if (t < PTS) {
        #pragma unroll
        for (int q = 0; q < 4; ++q) {      // chunks 4..7, still ascending
            #pragma unroll
            for (int r = 0; r < 3; ++r) {
                const float d  = sd[q][t][r];
                const int   ii = (int)si[q][t][r];
                INS(d, ii, e0,j0,e1,j1,e2,j2)
            }
        }
        const float r0 = 1.0f / (e0 + EPSV);
        const float r1 = 1.0f / (e1 + EPSV);
        const float r2 = 1.0f / (e2 + EPSV);
        const float rs = r0 + r1 + r2;
        const int gp = b * NN + tile * PTS + t;
        wgt4[gp] = make_float4(r0 / rs, r1 / rs, r2 / rs, 0.0f);
        idx4[gp] = make_int4(j0, j1, j2, 0);
    }
}

__global__ __launch_bounds__(NTH) void interp_kernel(
    const float* __restrict__ feats,
    const float4* __restrict__ wgt4,
    const int4*  __restrict__ idx4,
    float* __restrict__ out)
{
    __shared__ float fbuf[TC * MM];       // 32 KB

    const int tilesPerB = CC / TC;        // 64
    const int b  = blockIdx.x / tilesPerB;
    const int c0 = (blockIdx.x % tilesPerB) * TC;
    const int t  = threadIdx.x;

    const float4* src = reinterpret_cast<const float4*>(
        feats + ((size_t)b * CC + c0) * MM);
    #pragma unroll
    for (int i = t; i < TC * MM / 4; i += NTH)
        reinterpret_cast<float4*>(fbuf)[i] = src[i];
    __syncthreads();

    #pragma unroll 2
    for (int it = 0; it < NN / NTH; ++it) {
        const int n = it * NTH + t;
        const float4 w = wgt4[b * NN + n];
        const int4   j = idx4[b * NN + n];
        float* ob = out + ((size_t)b * CC + c0) * NN + n;
        #pragma unroll
        for (int cl = 0; cl < TC; ++cl) {
            const float* fr = fbuf + cl * MM;
            ob[(size_t)cl * NN] = w.x * fr[j.x] + w.y * fr[j.y] + w.z * fr[j.z];
        }
    }
}

extern "C" void kernel_launch(void* const* d_in, const int* in_sizes, int n_in,
                              void* d_out, int out_size, void* d_ws, size_t ws_size,
                              hipStream_t stream) {
    const float* unknown = (const float*)d_in[0];
    const float* known   = (const float*)d_in[1];
    const float* feats   = (const float*)d_in[2];
    float* out = (float*)d_out;

    float4* wgt4 = (float4*)d_ws;                       // 65536 * 16B = 1MB
    int4*   idx4 = (int4*)((char*)d_ws + (size_t)BB * NN * sizeof(float4));

    nn_scan_kernel<<<BB * (NN / PTS), NTH, 0, stream>>>(unknown, known, wgt4, idx4);
    interp_kernel<<<BB * (CC / TC), NTH, 0, stream>>>(feats, wgt4, idx4, out);
}

// Round 8
// 147.416 us; speedup vs baseline: 1.1502x; 1.1502x over previous
//
#include <hip/hip_runtime.h>

// PointnetFPModule: three_nn (brute force, top-3 smallest d2) + three_interpolate.
// Shapes: B=8, N=8192, M=2048, C=256.  All fp32.
// unknown (B,N,3), known (B,M,3), known_feats (B,C,M) -> out (B,C,N)
//
// R8: two-pass threshold scan, retuned after R7's regression:
//  - PPT=1 (64 pts/block): captures per wave-step = 64x4x3.3/2048 ~ 0.41
//    -> stage-2 capture branch taken ~33% of steps (R7: ~80% at PPT=4).
//  - grid 1024, LDS 41KB -> 3 blocks/CU = 24 waves/CU (R7: 8 waves/CU).
//  stage1: r = |k|^2 - 2u.k (3 FMA) + value-only top-3 (med3,med3,min)
//  merge -> T = 3rd-smallest r + 1e-4
//  stage2: recompute r bit-identically; rare branch computes canonical
//          bit-exact d2 + stable indexed insert. Margin 1e-4 >> 2*eps (~2e-6).

#define BB 8
#define NN 8192
#define MM 2048
#define CC 256
#define EPSV 1e-8f
#define NTH 512          // 8 waves
#define NCH 8            // chunks = waves
#define CHUNK (MM/NCH)   // 256
#define PTS 64           // points per block (1 per lane)
#define MARGIN 1e-4f
#define TC 4             // channels per interp block

// Branchy stable insert: strict < keeps lowest index on ties; candidates
// arrive in ascending-index order => matches jax.lax.top_k.
#define INS(dd, mi, D0,I0,D1,I1,D2,I2) \
    if ((dd) < D2) { \
        if ((dd) < D1) { D2 = D1; I2 = I1; \
            if ((dd) < D0) { D1 = D0; I1 = I0; D0 = (dd); I0 = (mi); } \
            else           { D1 = (dd); I1 = (mi); } \
        } else { D2 = (dd); I2 = (mi); } }

// Proxy rank value: MUST be bit-identical in stage1 and stage2.
#define RF(KX,KY,KZ,KQ) \
    __fmaf_rn((KZ), az, __fmaf_rn((KY), ay, __fmaf_rn((KX), ax, (KQ))))

// Stage-1 branchless 3-smallest (values only). Invariant R0<=R1<=R2.
#define S1(KX,KY,KZ,KQ) { \
    const float rr = RF(KX,KY,KZ,KQ); \
    R2 = __builtin_amdgcn_fmed3f(R1, R2, rr); \
    R1 = __builtin_amdgcn_fmed3f(R0, R1, rr); \
    R0 = fminf(R0, rr); }

// Stage-2 capture: exact d2 matches numpy (no FMA contraction, (x2+y2)+z2).
#define CAP(RR,KX,KY,KZ,MI) \
    if ((RR) <= Tm) { \
        const float dx = ux-(KX), dy = uy-(KY), dz = uz-(KZ); \
        const float d = __fadd_rn(__fadd_rn(__fmul_rn(dx,dx),__fmul_rn(dy,dy)),__fmul_rn(dz,dz)); \
        INS(d, MI, D0,J0,D1,J1,D2,J2) }

typedef unsigned short u16;

__global__ __launch_bounds__(NTH) void nn_scan_kernel(
    const float* __restrict__ unknown,
    const float* __restrict__ known,
    float4* __restrict__ wgt4,
    int4*  __restrict__ idx4)
{
    __shared__ float kxs[MM], kys[MM], kzs[MM], kqs[MM];   // 32 KB
    __shared__ float pd[NCH][PTS][3];                      // 6 KB (r-lists, then d2)
    __shared__ u16   si[NCH][PTS][3];                      // 3 KB
    __shared__ float Tarr[PTS];                            // 256 B

    const int tilesPerBatch = NN / PTS;   // 128
    const int b    = blockIdx.x / tilesPerBatch;
    const int tile = blockIdx.x % tilesPerBatch;
    const int t    = threadIdx.x;
    const int lane = t & 63;
    const int g    = t >> 6;              // wave id == chunk id (uniform/wave)

    // ---- stage known[b] (AoS -> SoA) + |k|^2 ----
    const float* kb = known + (size_t)b * MM * 3;
    for (int idx = t; idx < MM * 3; idx += NTH) {
        const float v  = kb[idx];
        const int   a  = idx % 3;
        const int   mi = idx / 3;
        float* dst = (a == 0) ? kxs : ((a == 1) ? kys : kzs);
        dst[mi] = v;
    }
    __syncthreads();
    for (int m = t; m < MM; m += NTH) {
        const float x = kxs[m], y = kys[m], z = kzs[m];
        kqs[m] = __fmaf_rn(z, z, __fmaf_rn(y, y, x * x));
    }

    // ---- one point per lane ----
    const float* u = unknown + ((size_t)b * NN + (size_t)tile * PTS + lane) * 3;
    const float ux = u[0], uy = u[1], uz = u[2];
    const float ax = -2.0f * ux, ay = -2.0f * uy, az = -2.0f * uz;
    __syncthreads();   // kqs ready

    // ---- stage 1: top-3 proxy values (no indices) ----
    float R0 = 1e30f, R1 = 1e30f, R2 = 1e30f;
    const int mbeg = g * CHUNK;
    #pragma unroll 4
    for (int m = mbeg; m < mbeg + CHUNK; m += 4) {
        const float4 x4 = *reinterpret_cast<const float4*>(&kxs[m]);
        const float4 y4 = *reinterpret_cast<const float4*>(&kys[m]);
        const float4 z4 = *reinterpret_cast<const float4*>(&kzs[m]);
        const float4 q4 = *reinterpret_cast<const float4*>(&kqs[m]);
        S1(x4.x, y4.x, z4.x, q4.x)
        S1(x4.y, y4.y, z4.y, q4.y)
        S1(x4.z, y4.z, z4.z, q4.z)
        S1(x4.w, y4.w, z4.w, q4.w)
    }
    pd[g][lane][0] = R0; pd[g][lane][1] = R1; pd[g][lane][2] = R2;
    __syncthreads();

    // ---- merge r-lists -> per-point threshold ----
    if (t < PTS) {
        float e0 = 1e30f, e1 = 1e30f, e2 = 1e30f;
        #pragma unroll
        for (int q = 0; q < NCH; ++q) {
            #pragma unroll
            for (int r = 0; r < 3; ++r) {
                const float d = pd[q][t][r];
                e2 = __builtin_amdgcn_fmed3f(e1, e2, d);
                e1 = __builtin_amdgcn_fmed3f(e0, e1, d);
                e0 = fminf(e0, d);
            }
        }
        Tarr[t] = e2 + MARGIN;
    }
    __syncthreads();

    // ---- stage 2: rescan; capture exact (d2, idx) where r <= T ----
    float D0 = 1e30f, D1 = 1e30f, D2 = 1e30f;
    int   J0 = 0,     J1 = 0,     J2 = 0;
    const float Tm = Tarr[lane];

    #pragma unroll 2
    for (int m = mbeg; m < mbeg + CHUNK; m += 4) {
        const float4 x4 = *reinterpret_cast<const float4*>(&kxs[m]);
        const float4 y4 = *reinterpret_cast<const float4*>(&kys[m]);
        const float4 z4 = *reinterpret_cast<const float4*>(&kzs[m]);
        const float4 q4 = *reinterpret_cast<const float4*>(&kqs[m]);
        const float rr0 = RF(x4.x, y4.x, z4.x, q4.x);
        const float rr1 = RF(x4.y, y4.y, z4.y, q4.y);
        const float rr2 = RF(x4.z, y4.z, z4.z, q4.z);
        const float rr3 = RF(x4.w, y4.w, z4.w, q4.w);
        if (fminf(fminf(rr0, rr1), fminf(rr2, rr3)) <= Tm) {
            CAP(rr0, x4.x, y4.x, z4.x, m)
            CAP(rr1, x4.y, y4.y, z4.y, m+1)
            CAP(rr2, x4.z, y4.z, z4.z, m+2)
            CAP(rr3, x4.w, y4.w, z4.w, m+3)
        }
    }

    // ---- writeback captured lists (reuse pd) + stable merge ----
    pd[g][lane][0] = D0; pd[g][lane][1] = D1; pd[g][lane][2] = D2;
    si[g][lane][0] = (u16)J0; si[g][lane][1] = (u16)J1; si[g][lane][2] = (u16)J2;
    __syncthreads();

    if (t < PTS) {
        float e0 = 1e30f, e1 = 1e30f, e2 = 1e30f;
        int   j0 = 0,     j1 = 0,     j2 = 0;
        #pragma unroll
        for (int q = 0; q < NCH; ++q) {     // chunk asc, rank asc => index asc
            #pragma unroll
            for (int r = 0; r < 3; ++r) {
                const float d  = pd[q][t][r];
                const int   ii = (int)si[q][t][r];
                INS(d, ii, e0,j0,e1,j1,e2,j2)
            }
        }
        const float r0 = 1.0f / (e0 + EPSV);
        const float r1 = 1.0f / (e1 + EPSV);
        const float r2 = 1.0f / (e2 + EPSV);
        const float rs = r0 + r1 + r2;
        const int gp = b * NN + tile * PTS + t;
        wgt4[gp] = make_float4(r0 / rs, r1 / rs, r2 / rs, 0.0f);
        idx4[gp] = make_int4(j0, j1, j2, 0);
    }
}

__global__ __launch_bounds__(NTH) void interp_kernel(
    const float* __restrict__ feats,
    const float4* __restrict__ wgt4,
    const int4*  __restrict__ idx4,
    float* __restrict__ out)
{
    __shared__ float fbuf[TC * MM];       // 32 KB

    const int tilesPerB = CC / TC;        // 64
    const int b  = blockIdx.x / tilesPerB;
    const int c0 = (blockIdx.x % tilesPerB) * TC;
    const int t  = threadIdx.x;

    const float4* src = reinterpret_cast<const float4*>(
        feats + ((size_t)b * CC + c0) * MM);
    #pragma unroll
    for (int i = t; i < TC * MM / 4; i += NTH)
        reinterpret_cast<float4*>(fbuf)[i] = src[i];
    __syncthreads();

    #pragma unroll 2
    for (int it = 0; it < NN / NTH; ++it) {
        const int n = it * NTH + t;
        const float4 w = wgt4[b * NN + n];
        const int4   j = idx4[b * NN + n];
        float* ob = out + ((size_t)b * CC + c0) * NN + n;
        #pragma unroll
        for (int cl = 0; cl < TC; ++cl) {
            const float* fr = fbuf + cl * MM;
            ob[(size_t)cl * NN] = w.x * fr[j.x] + w.y * fr[j.y] + w.z * fr[j.z];
        }
    }
}

extern "C" void kernel_launch(void* const* d_in, const int* in_sizes, int n_in,
                              void* d_out, int out_size, void* d_ws, size_t ws_size,
                              hipStream_t stream) {
    const float* unknown = (const float*)d_in[0];
    const float* known   = (const float*)d_in[1];
    const float* feats   = (const float*)d_in[2];
    float* out = (float*)d_out;

    float4* wgt4 = (float4*)d_ws;                       // 65536 * 16B = 1MB
    int4*   idx4 = (int4*)((char*)d_ws + (size_t)BB * NN * sizeof(float4));

    nn_scan_kernel<<<BB * (NN / PTS), NTH, 0, stream>>>(unknown, known, wgt4, idx4);
    interp_kernel<<<BB * (CC / TC), NTH, 0, stream>>>(feats, wgt4, idx4, out);
}